// Round 4
// baseline (1399.021 us; speedup 1.0000x reference)
//
#include <hip/hip_runtime.h>
#include <hip/hip_bf16.h>

// ---------------- problem constants ----------------
#define B_      512
#define KD_     256
#define VD_     512
#define M_      100000
#define NPS     1563        // ceil(100000/64) blocks for k_ps
#define NST     391         // ceil(100000/256) slot tiles for k_sim
#define CPR2    (NST*8)     // candidates per row = 3128

// output element offsets (concatenated tuple, flat)
#define OUT_COMPOSED 0L
#define OUT_IDX      524288L
#define OUT_SIMV     528384L
#define OUT_GATT     532480L
#define OUT_SELIDX   864256L

typedef __attribute__((ext_vector_type(8))) short bf16x8;
typedef __attribute__((ext_vector_type(4))) float f32x4;

// workspace float-element offsets (keep 16-float alignment for bf16 regions)
static constexpr long WS_FLAG = 0;
static constexpr long WS_QK   = 64;                  // 131072
static constexpr long WS_KPW  = WS_QK + 131072;      // 65536 (kp_w natural [i][j], f32)
static constexpr long WS_KPB  = WS_KPW + 65536;      // 256
static constexpr long WS_OUT  = WS_KPB + 256;        // 262144
static constexpr long WS_GATW = WS_OUT + 262144;     // 262144
static constexpr long WS_GAS  = WS_GATW + 262144;    // 512
static constexpr long WS_GAD  = WS_GAS + 512;        // 512
static constexpr long WS_GAW  = WS_GAD + 512;        // 512
static constexpr long WS_GAB  = WS_GAW + 512;        // 64
static constexpr long WS_S1   = WS_GAB + 64;         // 512
static constexpr long WS_S2   = WS_S1 + 512;         // 512
static constexpr long WS_PKN  = WS_S2 + 512;         // 131072 (pk normalized f32)
static constexpr long WS_SELI = WS_PKN + 131072;     // int[512*8]
static constexpr long WS_PKBF = WS_SELI + 4096;      // bf16[512*256]  = 65536 floats
static constexpr long WS_KPWB = WS_PKBF + 65536;     // bf16[256*256]  = 32768 floats
static constexpr long WS_PSBF = WS_KPWB + 32768;     // bf16[100000*256] = 12800000 floats
static constexpr long WS_CANDV= WS_PSBF + 12800000;  // float[512*CPR2]
static constexpr long WS_CANDI= WS_CANDV + (long)CPR2 * B_; // int[512*CPR2]

// ---------------- helpers ----------------
__device__ __forceinline__ float ldf(const void* p, long i, int isbf) {
  if (isbf) {
    unsigned short u = ((const unsigned short*)p)[i];
    return __uint_as_float(((unsigned)u) << 16);
  }
  return ((const float*)p)[i];
}
__device__ __forceinline__ void stf(void* p, long i, float v, int isbf) {
  if (isbf) ((__hip_bfloat16*)p)[i] = __float2bfloat16(v);
  else ((float*)p)[i] = v;
}
__device__ __forceinline__ unsigned short f2bf(float f) {
  union { float f; unsigned u; } x; x.f = f;
  unsigned r = x.u + 0x7FFFu + ((x.u >> 16) & 1u);   // RNE
  return (unsigned short)(r >> 16);
}

// ---------------- K0: detect input dtype ----------------
__global__ void k_detect(const unsigned* s1, int* flag) {
  if (threadIdx.x == 0) {
    unsigned w = s1[0];
    *flag = ((w & 0x7FFF7FFFu) == 0x3F803F80u) ? 1 : 0;
  }
}

// ---------------- K1: stage constants as f32 (+bf16 kp_w) in ws ----------------
__global__ void k_prep(const void* qk, const void* kpw, const void* kpb,
                       const void* outp, const void* gatw, const void* gas,
                       const void* gad, const void* gaw, const void* gab,
                       const void* s1, const void* s2, float* ws) {
  const int isbf = *(const int*)ws;
  long t = (long)blockIdx.x * blockDim.x + threadIdx.x;
  long stride = (long)gridDim.x * blockDim.x;
  unsigned short* kpwb = (unsigned short*)(ws + WS_KPWB);
  for (long i = t; i < 131072; i += stride) ws[WS_QK + i]  = ldf(qk, i, isbf);
  for (long i = t; i < 65536;  i += stride) {
    float v = ldf(kpw, i, isbf);
    ws[WS_KPW + i] = v;
    kpwb[i] = f2bf(v);
  }
  for (long i = t; i < 256;    i += stride) ws[WS_KPB + i] = ldf(kpb, i, isbf);
  for (long i = t; i < 262144; i += stride) ws[WS_OUT + i] = ldf(outp, i, isbf);
  for (long i = t; i < 262144; i += stride) ws[WS_GATW + i]= ldf(gatw, i, isbf);
  for (long i = t; i < 512;    i += stride) ws[WS_GAS + i] = ldf(gas, i, isbf);
  for (long i = t; i < 512;    i += stride) ws[WS_GAD + i] = ldf(gad, i, isbf);
  for (long i = t; i < 512;    i += stride) ws[WS_GAW + i] = ldf(gaw, i, isbf);
  for (long i = t; i < 1;      i += stride) ws[WS_GAB + i] = ldf(gab, i, isbf);
  for (long i = t; i < 512;    i += stride) ws[WS_S1 + i]  = ldf(s1, i, isbf);
  for (long i = t; i < 512;    i += stride) ws[WS_S2 + i]  = ldf(s2, i, isbf);
}

// ---------------- K2: pk_n = normalize(qk @ kp_w^T + b), f32 + bf16 copies ----------------
__global__ void k_pk(float* ws) {
  __shared__ float qk_s[8][256];
  __shared__ float pk_s[8][260];
  __shared__ float kw_s[32][260];
  __shared__ float red[8][32];
  __shared__ float invs[8];
  const int t = threadIdx.x, blk = blockIdx.x;
  for (int n = 0; n < 2; ++n) {
    int e4 = t + 256 * n;
    int r = e4 >> 6, j4 = e4 & 63;
    *(float4*)&qk_s[r][j4 * 4] =
      *(const float4*)&ws[WS_QK + (long)(blk * 8 + r) * 256 + j4 * 4];
  }
  const int il = t & 31, rg = t >> 5;
  for (int tile = 0; tile < 8; ++tile) {
    __syncthreads();
    for (int n = 0; n < 8; ++n) {
      int e4 = t + 256 * n;
      int ii = e4 >> 6, j4 = e4 & 63;
      *(float4*)&kw_s[ii][j4 * 4] =
        *(const float4*)&ws[WS_KPW + (long)(tile * 32 + ii) * 256 + j4 * 4];
    }
    __syncthreads();
    float acc = 0.f;
    for (int j = 0; j < 256; j += 4) {
      float4 a = *(const float4*)&qk_s[rg][j];
      float4 k4 = *(const float4*)&kw_s[il][j];
      acc += a.x * k4.x + a.y * k4.y + a.z * k4.z + a.w * k4.w;
    }
    pk_s[rg][tile * 32 + il] = acc + ws[WS_KPB + tile * 32 + il];
  }
  __syncthreads();
  {
    int r = t >> 5, c = t & 31;
    float s = 0.f;
    for (int q = 0; q < 8; ++q) { float v = pk_s[r][c + 32 * q]; s += v * v; }
    red[r][c] = s;
  }
  __syncthreads();
  if (t < 8) {
    float s = 0.f;
    for (int c = 0; c < 32; ++c) s += red[t][c];
    invs[t] = (float)(1.0 / fmax(sqrt((double)s), 1e-8));
  }
  __syncthreads();
  unsigned short* pkbf = (unsigned short*)(ws + WS_PKBF);
  for (int n = 0; n < 8; ++n) {
    int e = t + 256 * n;
    int r = e >> 8, i = e & 255;
    float pv = pk_s[r][i] * invs[r];
    long gi = (long)(blk * 8 + r) * 256 + i;
    ws[WS_PKN + gi] = pv;
    pkbf[gi] = f2bf(pv);
  }
}

// ---------------- K3a: ps projection via MFMA -> normalized bf16 ps rows ----------------
// 1563 blocks x 256 threads (4 waves), each block = 64 slots.
__global__ void __launch_bounds__(256) k_ps(const void* key_store, float* ws) {
  __shared__ unsigned short key_s[64 * 264];     // 33792 B (pad 8 bf16/row)
  const int isbf = *(const int*)ws;
  const int t = threadIdx.x;
  const long m_base = (long)blockIdx.x * 64;
  const unsigned short* kpwb = (const unsigned short*)(ws + WS_KPWB);
  unsigned short* psbf = (unsigned short*)(ws + WS_PSBF);

  if (isbf) {
    const unsigned short* kp = (const unsigned short*)key_store;
    for (int n = 0; n < 16; ++n) {
      int idx = t + 256 * n;                     // 4096 4-elem chunks
      int m = idx >> 6, j4 = idx & 63;
      uint2 u = make_uint2(0u, 0u);
      if (m_base + m < M_) u = *(const uint2*)&kp[(m_base + m) * 256 + j4 * 4];
      *(uint2*)&key_s[m * 264 + j4 * 4] = u;
    }
  } else {
    const float* kp = (const float*)key_store;
    for (int n = 0; n < 16; ++n) {
      int idx = t + 256 * n;
      int m = idx >> 6, j4 = idx & 63;
      uint2 u = make_uint2(0u, 0u);
      if (m_base + m < M_) {
        float4 v = *(const float4*)&kp[(m_base + m) * 256 + j4 * 4];
        u.x = (unsigned)f2bf(v.x) | ((unsigned)f2bf(v.y) << 16);
        u.y = (unsigned)f2bf(v.z) | ((unsigned)f2bf(v.w) << 16);
      }
      *(uint2*)&key_s[m * 264 + j4 * 4] = u;
    }
  }
  __syncthreads();

  const int lane = t & 63, wv = t >> 6;
  const int n16 = lane & 15, quad = lane >> 4;
  f32x4 acc[16] = {};
  const unsigned short* arow = &key_s[(wv * 16 + n16) * 264];
  for (int ks = 0; ks < 8; ++ks) {
    bf16x8 a = *(const bf16x8*)&arow[ks * 32 + quad * 8];
    const unsigned short* bp = kpwb + n16 * 256 + ks * 32 + quad * 8;
    #pragma unroll
    for (int it = 0; it < 16; ++it) {
      bf16x8 b = *(const bf16x8*)&bp[it * 4096];
      acc[it] = __builtin_amdgcn_mfma_f32_16x16x32_bf16(a, b, acc[it], 0, 0, 0);
    }
  }
  // bias + row norms (rows m = wv*16 + quad*4 + r; cols i = it*16 + n16)
  float ss[4] = {0.f, 0.f, 0.f, 0.f};
  #pragma unroll
  for (int it = 0; it < 16; ++it) {
    float bias = ws[WS_KPB + it * 16 + n16];
    acc[it][0] += bias; acc[it][1] += bias; acc[it][2] += bias; acc[it][3] += bias;
    #pragma unroll
    for (int r = 0; r < 4; ++r) ss[r] += acc[it][r] * acc[it][r];
  }
  #pragma unroll
  for (int r = 0; r < 4; ++r) {
    ss[r] += __shfl_xor(ss[r], 1); ss[r] += __shfl_xor(ss[r], 2);
    ss[r] += __shfl_xor(ss[r], 4); ss[r] += __shfl_xor(ss[r], 8);
    ss[r] = 1.0f / fmaxf(sqrtf(ss[r]), 1e-8f);
  }
  // normalized bf16 back into LDS (per-wave-disjoint rows; no barrier needed)
  #pragma unroll
  for (int it = 0; it < 16; ++it) {
    int col = it * 16 + n16;
    #pragma unroll
    for (int r = 0; r < 4; ++r)
      key_s[(wv * 16 + quad * 4 + r) * 264 + col] = f2bf(acc[it][r] * ss[r]);
  }
  __syncthreads();
  // coalesced store to ws psbf [m][256] bf16
  for (int n = 0; n < 8; ++n) {
    int idx = t + 256 * n;                       // 2048 8-elem chunks
    int m = idx >> 5, c8 = idx & 31;
    if (m_base + m < M_)
      *(uint4*)&psbf[(m_base + m) * 256 + c8 * 8] =
        *(const uint4*)&key_s[m * 264 + c8 * 8];
  }
}

// ---------------- K3b: sim via MFMA + per-256-slot-chunk exact top-8 ----------------
// v3: XCD-affine swizzle — the 8 qtile-blocks sharing a stile get the SAME
// bid%8 (same XCD under round-robin dispatch) and are consecutive in that
// XCD's issue order, so 7/8 reads of the stile's psbf slice hit that XCD's
// L2 instead of re-fetching HBM (FETCH 203MB -> ~75MB). B-fragments are
// double-buffered (bb[2][8], compile-time indices) so 8 loads stay in
// flight during MFMA. 512 threads, 75KB LDS -> 2 blocks/CU.
#define SIMW 261
__global__ void __launch_bounds__(512, 4) k_sim(float* ws) {
  extern __shared__ char smem8[];
  unsigned short* pk_s = (unsigned short*)smem8;            // 64 x 264 bf16 = 33792 B
  float* simt  = (float*)smem8;                             // 64 x 261 f32 = 66816 B (aliases pk_s, used after MFMA)
  float* candv = (float*)(smem8 + 66816);                   // 128 x 8
  int*   candi = (int*)(smem8 + 66816 + 4096);              // 128 x 8

  const int t = threadIdx.x;
  // XCD-affine mapping: grid = 49*64 = 3136; stile = grp*8 + (bid&7)
  const int bid = blockIdx.x;
  const int qtile = (bid >> 3) & 7;
  const int stile = (bid >> 6) * 8 + (bid & 7);
  if (stile >= NST) return;                     // 8 dead blocks (stile 391)
  const int qbase = qtile * 64;
  const long sbase = (long)stile * 256;
  const unsigned short* pkbf = (const unsigned short*)(ws + WS_PKBF);
  const unsigned short* psbf = (const unsigned short*)(ws + WS_PSBF);

  // stage pk tile [64][256] -> [64][264]
  for (int n = 0; n < 4; ++n) {
    int idx = t + 512 * n;                       // 2048 8-elem chunks
    int m = idx >> 5, c8 = idx & 31;
    *(uint4*)&pk_s[m * 264 + c8 * 8] =
      *(const uint4*)&pkbf[(long)(qbase + m) * 256 + c8 * 8];
  }
  __syncthreads();

  const int lane = t & 63, wv = t >> 6;
  const int n16 = lane & 15, quad = lane >> 4;
  const int m0 = (wv >> 2) * 32, s0 = (wv & 3) * 64;
  f32x4 acc[2][4] = {};

  // per-lane B row pointers into global psbf (clamp OOB rows of last stile;
  // their sim columns are never scanned, value is irrelevant)
  const unsigned short* bp[4];
  #pragma unroll
  for (int sf = 0; sf < 4; ++sf) {
    long srow = sbase + s0 + sf * 16 + n16;
    if (srow >= M_) srow = 0;
    bp[sf] = psbf + srow * 256 + quad * 8;
  }

  // double-buffered B fragments: prefetch kq+1 while MFMAing kq
  bf16x8 bb[2][8];
  #pragma unroll
  for (int ks = 0; ks < 2; ++ks)
    #pragma unroll
    for (int sf = 0; sf < 4; ++sf)
      bb[0][ks * 4 + sf] = *(const bf16x8*)&bp[sf][ks * 32];

  #pragma unroll
  for (int kq = 0; kq < 4; ++kq) {               // 4 K-quarters of 64
    if (kq < 3) {
      #pragma unroll
      for (int ks = 0; ks < 2; ++ks)
        #pragma unroll
        for (int sf = 0; sf < 4; ++sf)
          bb[(kq + 1) & 1][ks * 4 + sf] =
            *(const bf16x8*)&bp[sf][(kq + 1) * 64 + ks * 32];
    }
    #pragma unroll
    for (int ks = 0; ks < 2; ++ks) {
      const int kb = kq * 64 + ks * 32;
      bf16x8 a0 = *(const bf16x8*)&pk_s[(m0 + n16) * 264 + kb + quad * 8];
      bf16x8 a1 = *(const bf16x8*)&pk_s[(m0 + 16 + n16) * 264 + kb + quad * 8];
      #pragma unroll
      for (int sf = 0; sf < 4; ++sf) {
        acc[0][sf] = __builtin_amdgcn_mfma_f32_16x16x32_bf16(a0, bb[kq & 1][ks * 4 + sf], acc[0][sf], 0, 0, 0);
        acc[1][sf] = __builtin_amdgcn_mfma_f32_16x16x32_bf16(a1, bb[kq & 1][ks * 4 + sf], acc[1][sf], 0, 0, 0);
      }
    }
  }
  __syncthreads();                               // pk_s reads done; simt may overwrite
  // write sim tile to LDS (C/D layout: col = lane&15, row = quad*4+reg)
  #pragma unroll
  for (int qf = 0; qf < 2; ++qf)
    #pragma unroll
    for (int sf = 0; sf < 4; ++sf)
      #pragma unroll
      for (int r = 0; r < 4; ++r)
        simt[(m0 + qf * 16 + quad * 4 + r) * SIMW + s0 + sf * 16 + n16] = acc[qf][sf][r];
  __syncthreads();
  // per-row top-8 over 256 slots: 2 threads/row scan 128 each, then merge
  if (t < 128) {
    int row = t >> 1, half = t & 1;
    int sv = (int)(M_ - sbase);
    int lo = half * 128;
    int mmax = sv - lo; if (mmax > 128) mmax = 128; if (mmax < 0) mmax = 0;
    float tv[8]; int ti[8];
    #pragma unroll
    for (int q = 0; q < 8; ++q) { tv[q] = -3.0e38f; ti[q] = 0x7FFFFFFF; }
    for (int m = 0; m < mmax; ++m) {
      float v = simt[row * SIMW + lo + m];
      if (v > tv[7]) {
        int s = (int)(sbase + lo + m);
        bool placed = false;
        #pragma unroll
        for (int q = 7; q >= 1; --q) {
          if (!placed) {
            if (v > tv[q - 1]) { tv[q] = tv[q - 1]; ti[q] = ti[q - 1]; }
            else { tv[q] = v; ti[q] = s; placed = true; }
          }
        }
        if (!placed) { tv[0] = v; ti[0] = s; }
      }
    }
    #pragma unroll
    for (int q = 0; q < 8; ++q) { candv[t * 8 + q] = tv[q]; candi[t * 8 + q] = ti[q]; }
  }
  __syncthreads();
  if (t < 64) {
    const float* av = &candv[(2 * t) * 8];
    const float* bv = &candv[(2 * t + 1) * 8];
    const int* ai = &candi[(2 * t) * 8];
    const int* bi = &candi[(2 * t + 1) * 8];
    float* cv = ws + WS_CANDV;
    int* ci = (int*)(ws + WS_CANDI);
    long ob = (long)(qbase + t) * CPR2 + (long)stile * 8;
    int ia = 0, ib = 0;
    #pragma unroll
    for (int q = 0; q < 8; ++q) {
      bool ta;
      if (ia >= 8) ta = false;
      else if (ib >= 8) ta = true;
      else {
        float va = av[ia], vb = bv[ib];
        ta = (va > vb) || (va == vb && ai[ia] <= bi[ib]);
      }
      if (ta) { cv[ob + q] = av[ia]; ci[ob + q] = ai[ia]; ++ia; }
      else    { cv[ob + q] = bv[ib]; ci[ob + q] = bi[ib]; ++ib; }
    }
  }
}

// ---------------- K4: per-row merge -> top16 -> f64 rescore -> top8 ----------------
__global__ void k_topk(const void* key_store, const void* idx_store,
                       float* ws, void* dout) {
  __shared__ unsigned long long keys[256 * 16];
  __shared__ unsigned long long redk[256];
  __shared__ unsigned long long res[16];
  __shared__ int cidx[16];
  __shared__ double rv[16];
  const int isbf = *(const int*)ws;
  const int t = threadIdx.x, b = blockIdx.x;
  unsigned long long* ml = &keys[t * 16];
  #pragma unroll
  for (int q = 0; q < 16; ++q) ml[q] = 0ull;
  const float* cv = ws + WS_CANDV;
  const int* ci = (const int*)(ws + WS_CANDI);
  long base = (long)b * CPR2;
  for (int cc = t; cc < CPR2; cc += 256) {
    float v = cv[base + cc];
    unsigned id = (unsigned)ci[base + cc];
    unsigned bb = __float_as_uint(v);
    unsigned o = (bb & 0x80000000u) ? ~bb : (bb | 0x80000000u);
    unsigned long long key = ((unsigned long long)o << 32) |
                             (unsigned long long)(0xFFFFFFFFu - id);
    if (key > ml[15]) {
      int q = 15;
      while (q > 0 && key > ml[q - 1]) { ml[q] = ml[q - 1]; --q; }
      ml[q] = key;
    }
  }
  __syncthreads();
  int h = 0;
  for (int r = 0; r < 16; ++r) {
    redk[t] = (h < 16) ? ml[h] : 0ull;
    __syncthreads();
    for (int s = 128; s > 0; s >>= 1) {
      if (t < s) { if (redk[t + s] > redk[t]) redk[t] = redk[t + s]; }
      __syncthreads();
    }
    unsigned long long win = redk[0];
    if (h < 16 && ml[h] == win) ++h;
    if (t == 0) res[r] = win;
    __syncthreads();
  }
  if (t < 16) cidx[t] = (int)(0xFFFFFFFFu - (unsigned)(res[t] & 0xFFFFFFFFu));
  __syncthreads();
  // f64 rescore of 16 candidates (16 threads per candidate)
  {
    int cand = t >> 4, p = t & 15;
    long m = (long)cidx[cand];
    double dp = 0.0, nr = 0.0;
    for (int ii = 0; ii < 16; ++ii) {
      int i = p * 16 + ii;
      double s = (double)ws[WS_KPB + i];
      const float* wrow = ws + WS_KPW + (long)i * 256;
      if (isbf) {
        const unsigned short* kr = (const unsigned short*)key_store + m * 256;
        for (int j = 0; j < 256; ++j)
          s += (double)__uint_as_float((unsigned)kr[j] << 16) * (double)wrow[j];
      } else {
        const float* kr = (const float*)key_store + m * 256;
        for (int j = 0; j < 256; ++j)
          s += (double)kr[j] * (double)wrow[j];
      }
      dp += s * (double)ws[WS_PKN + (long)b * 256 + i];
      nr += s * s;
    }
    dp += __shfl_xor(dp, 1); nr += __shfl_xor(nr, 1);
    dp += __shfl_xor(dp, 2); nr += __shfl_xor(nr, 2);
    dp += __shfl_xor(dp, 4); nr += __shfl_xor(nr, 4);
    dp += __shfl_xor(dp, 8); nr += __shfl_xor(nr, 8);
    if (p == 0) rv[cand] = dp / fmax(sqrt(nr), 1e-8);
  }
  __syncthreads();
  if (t == 0) {
    int ordr[16];
    for (int q = 0; q < 16; ++q) ordr[q] = q;
    for (int a = 0; a < 8; ++a) {
      int best = a;
      for (int x = a + 1; x < 16; ++x) {
        int xi = ordr[x], bi = ordr[best];
        if (rv[xi] > rv[bi] || (rv[xi] == rv[bi] && cidx[xi] < cidx[bi])) best = x;
      }
      int tmp = ordr[a]; ordr[a] = ordr[best]; ordr[best] = tmp;
    }
    int* seli = (int*)(ws + WS_SELI);
    for (int r = 0; r < 8; ++r) {
      int m = cidx[ordr[r]];
      stf(dout, OUT_IDX + b * 8 + r, (float)m, isbf);
      stf(dout, OUT_SIMV + b * 8 + r, (float)rv[ordr[r]], isbf);
      stf(dout, OUT_SELIDX + b * 8 + r, ldf(idx_store, m, isbf), isbf);
      seli[b * 8 + r] = m;
    }
  }
}

// ---------------- K5: GAT compose + count-sketch + circular conv ----------------
__global__ void k_compose(const void* value_store, const int* h1, const int* h2,
                          float* ws, void* dout) {
  __shared__ float feats[9][512];
  __shared__ float Wh[9][512];
  __shared__ float g0[9][8];
  __shared__ float sd_[2][9][8];
  __shared__ float psi1[512], psi2[512], pooled[512];
  __shared__ float wk[9];
  __shared__ float redz[40];
  __shared__ int sel[8];
  const int isbf = *(const int*)ws;
  const int t = threadIdx.x, b = blockIdx.x;
  if (t < 8) sel[t] = ((const int*)(ws + WS_SELI))[b * 8 + t];
  feats[0][t]       = ws[WS_OUT + (long)b * 512 + t];
  feats[0][t + 256] = ws[WS_OUT + (long)b * 512 + t + 256];
  __syncthreads();
  for (int n = 0; n < 16; ++n) {
    int e = t + 256 * n;
    int r = e >> 9, d = e & 511;
    feats[1 + r][d] = ldf(value_store, (long)sel[r] * 512 + d, isbf);
  }
  __syncthreads();
  {
    const int he0 = t, he1 = t + 256;
    float a0[9] = {}, a1[9] = {};
    const float* gw = ws + WS_GATW;
    for (int d = 0; d < 512; ++d) {
      float w0 = gw[(long)d * 512 + he0];
      float w1 = gw[(long)d * 512 + he1];
      #pragma unroll
      for (int k = 0; k < 9; ++k) {
        float a = feats[k][d];
        a0[k] += a * w0;
        a1[k] += a * w1;
      }
    }
    #pragma unroll
    for (int k = 0; k < 9; ++k) { Wh[k][he0] = a0[k]; Wh[k][he1] = a1[k]; }
  }
  __syncthreads();
  if (t < 144) {
    int k = t >> 4, rem = t & 15, hh = rem >> 1, sdx = rem & 1;
    const float* av = ws + (sdx ? WS_GAD : WS_GAS) + hh * 64;
    float s = 0.f;
    for (int e = 0; e < 64; ++e) s += Wh[k][hh * 64 + e] * av[e];
    sd_[sdx][k][hh] = s;
  }
  __syncthreads();
  if (t < 8) {
    float L[9], mx = -3e38f;
    for (int j = 0; j < 9; ++j) {
      float x = sd_[0][0][t] + sd_[1][j][t];
      L[j] = x > 0.f ? x : 0.2f * x;
      mx = fmaxf(mx, L[j]);
    }
    float ssum = 0.f;
    for (int j = 0; j < 9; ++j) { L[j] = expf(L[j] - mx); ssum += L[j]; }
    for (int j = 0; j < 9; ++j) g0[j][t] = L[j] / ssum;
  }
  __syncthreads();
  for (int n = 0; n < 3; ++n) {
    int e = t + 256 * n;
    if (e < 648) {
      int i = e / 72, rem = e % 72, j = rem >> 3, hh = rem & 7;
      float v = (i == 0) ? g0[j][hh] : ((i == j) ? 1.0f : 0.0f);
      stf(dout, OUT_GATT + (long)b * 648 + e, v, isbf);
    }
  }
  __syncthreads();
  #pragma unroll
  for (int i = 0; i < 9; ++i) {
    for (int half = 0; half < 2; ++half) {
      int d = t + half * 256;
      float x;
      if (i == 0) {
        int hh = d >> 6;
        x = 0.f;
        #pragma unroll
        for (int j = 0; j < 9; ++j) x += g0[j][hh] * Wh[j][d];
      } else x = Wh[i][d];
      feats[i][d] = x > 0.f ? x : expm1f(x);
    }
  }
  __syncthreads();
  {
    float part[9];
    const float* aw = ws + WS_GAW;
    #pragma unroll
    for (int k = 0; k < 9; ++k)
      part[k] = feats[k][t] * aw[t] + feats[k][t + 256] * aw[t + 256];
    #pragma unroll
    for (int k = 0; k < 9; ++k) {
      float s = part[k];
      s += __shfl_xor(s, 1);  s += __shfl_xor(s, 2);  s += __shfl_xor(s, 4);
      s += __shfl_xor(s, 8);  s += __shfl_xor(s, 16); s += __shfl_xor(s, 32);
      if ((t & 63) == 0) redz[(t >> 6) * 9 + k] = s;
    }
  }
  __syncthreads();
  if (t == 0) {
    float l[9], mx = -3e38f;
    for (int k = 0; k < 9; ++k) {
      l[k] = redz[k] + redz[9 + k] + redz[18 + k] + redz[27 + k] + ws[WS_GAB];
      mx = fmaxf(mx, l[k]);
    }
    float ssum = 0.f;
    for (int k = 0; k < 9; ++k) { l[k] = expf(l[k] - mx); ssum += l[k]; }
    for (int k = 0; k < 9; ++k) wk[k] = l[k] / ssum;
  }
  __syncthreads();
  for (int half = 0; half < 2; ++half) {
    int d = t + half * 256;
    float s = 0.f;
    #pragma unroll
    for (int k = 0; k < 9; ++k) s += wk[k] * feats[k][d];
    pooled[d] = s;
    psi1[d] = 0.f; psi2[d] = 0.f;
  }
  __syncthreads();
  for (int half = 0; half < 2; ++half) {
    int j = t + half * 256;
    atomicAdd(&psi1[h1[j]], ws[WS_OUT + (long)b * 512 + j] * ws[WS_S1 + j]);
    atomicAdd(&psi2[h2[j]], pooled[j] * ws[WS_S2 + j]);
  }
  __syncthreads();
  for (int half = 0; half < 2; ++half) {
    int tt = t + half * 256;
    float s = 0.f;
    for (int j = 0; j < 512; ++j) s += psi1[j] * psi2[(tt - j) & 511];
    stf(dout, OUT_COMPOSED + (long)b * 1024 + tt, s, isbf);
    stf(dout, OUT_COMPOSED + (long)b * 1024 + 512 + tt,
        ws[WS_OUT + (long)b * 512 + tt], isbf);
  }
}

// ---------------- launch ----------------
extern "C" void kernel_launch(void* const* d_in, const int* in_sizes, int n_in,
                              void* d_out, int out_size, void* d_ws, size_t ws_size,
                              hipStream_t stream) {
  float* ws = (float*)d_ws;
  k_detect<<<1, 64, 0, stream>>>((const unsigned*)d_in[15], (int*)d_ws);
  k_prep<<<512, 256, 0, stream>>>(d_in[1], d_in[6], d_in[7], d_in[0], d_in[8],
                                  d_in[9], d_in[10], d_in[11], d_in[12],
                                  d_in[15], d_in[16], ws);
  k_pk<<<64, 256, 0, stream>>>(ws);
  k_ps<<<NPS, 256, 0, stream>>>(d_in[3], ws);
  size_t smem = 75008;                          // pk 33792 | simt 66816 + cand 8192
  hipFuncSetAttribute((const void*)k_sim,
                      hipFuncAttributeMaxDynamicSharedMemorySize, (int)smem);
  k_sim<<<49 * 64, 512, smem, stream>>>(ws);    // XCD-affine: 3136 blocks
  k_topk<<<512, 256, 0, stream>>>(d_in[3], d_in[5], ws, d_out);
  k_compose<<<512, 256, 0, stream>>>(d_in[4], (const int*)d_in[13],
                                     (const int*)d_in[14], ws, d_out);
}

// Round 5
// 1055.122 us; speedup vs baseline: 1.3259x; 1.3259x over previous
//
#include <hip/hip_runtime.h>
#include <hip/hip_bf16.h>

// ---------------- problem constants ----------------
#define B_      512
#define KD_     256
#define VD_     512
#define M_      100000
#define NPS     1563        // ceil(100000/64) blocks for k_ps
#define NST     391         // ceil(100000/256) slot tiles for k_sim
#define CPR2    (NST*8)     // candidates per row = 3128

// output element offsets (concatenated tuple, flat)
#define OUT_COMPOSED 0L
#define OUT_IDX      524288L
#define OUT_SIMV     528384L
#define OUT_GATT     532480L
#define OUT_SELIDX   864256L

typedef __attribute__((ext_vector_type(8))) short bf16x8;
typedef __attribute__((ext_vector_type(4))) float f32x4;

// workspace float-element offsets (keep 16-float alignment for bf16 regions)
static constexpr long WS_FLAG = 0;
static constexpr long WS_QK   = 64;                  // 131072
static constexpr long WS_KPW  = WS_QK + 131072;      // 65536 (kp_w natural [i][j], f32)
static constexpr long WS_KPB  = WS_KPW + 65536;      // 256
static constexpr long WS_OUT  = WS_KPB + 256;        // 262144
static constexpr long WS_GATW = WS_OUT + 262144;     // 262144
static constexpr long WS_GAS  = WS_GATW + 262144;    // 512
static constexpr long WS_GAD  = WS_GAS + 512;        // 512
static constexpr long WS_GAW  = WS_GAD + 512;        // 512
static constexpr long WS_GAB  = WS_GAW + 512;        // 64
static constexpr long WS_S1   = WS_GAB + 64;         // 512
static constexpr long WS_S2   = WS_S1 + 512;         // 512
static constexpr long WS_PKN  = WS_S2 + 512;         // 131072 (pk normalized f32)
static constexpr long WS_SELI = WS_PKN + 131072;     // int[512*8]
static constexpr long WS_PKBF = WS_SELI + 4096;      // bf16[512*256]  = 65536 floats
static constexpr long WS_KPWB = WS_PKBF + 65536;     // bf16[256*256]  = 32768 floats
static constexpr long WS_PSBF = WS_KPWB + 32768;     // bf16[100000*256] = 12800000 floats
static constexpr long WS_CANDV= WS_PSBF + 12800000;  // float[512*CPR2]
static constexpr long WS_CANDI= WS_CANDV + (long)CPR2 * B_; // int[512*CPR2]

// ---------------- helpers ----------------
__device__ __forceinline__ float ldf(const void* p, long i, int isbf) {
  if (isbf) {
    unsigned short u = ((const unsigned short*)p)[i];
    return __uint_as_float(((unsigned)u) << 16);
  }
  return ((const float*)p)[i];
}
__device__ __forceinline__ void stf(void* p, long i, float v, int isbf) {
  if (isbf) ((__hip_bfloat16*)p)[i] = __float2bfloat16(v);
  else ((float*)p)[i] = v;
}
__device__ __forceinline__ unsigned short f2bf(float f) {
  union { float f; unsigned u; } x; x.f = f;
  unsigned r = x.u + 0x7FFFu + ((x.u >> 16) & 1u);   // RNE
  return (unsigned short)(r >> 16);
}

// ---------------- K0: detect input dtype ----------------
__global__ void k_detect(const unsigned* s1, int* flag) {
  if (threadIdx.x == 0) {
    unsigned w = s1[0];
    *flag = ((w & 0x7FFF7FFFu) == 0x3F803F80u) ? 1 : 0;
  }
}

// ---------------- K1: stage constants as f32 (+bf16 kp_w) in ws ----------------
__global__ void k_prep(const void* qk, const void* kpw, const void* kpb,
                       const void* outp, const void* gatw, const void* gas,
                       const void* gad, const void* gaw, const void* gab,
                       const void* s1, const void* s2, float* ws) {
  const int isbf = *(const int*)ws;
  long t = (long)blockIdx.x * blockDim.x + threadIdx.x;
  long stride = (long)gridDim.x * blockDim.x;
  unsigned short* kpwb = (unsigned short*)(ws + WS_KPWB);
  for (long i = t; i < 131072; i += stride) ws[WS_QK + i]  = ldf(qk, i, isbf);
  for (long i = t; i < 65536;  i += stride) {
    float v = ldf(kpw, i, isbf);
    ws[WS_KPW + i] = v;
    kpwb[i] = f2bf(v);
  }
  for (long i = t; i < 256;    i += stride) ws[WS_KPB + i] = ldf(kpb, i, isbf);
  for (long i = t; i < 262144; i += stride) ws[WS_OUT + i] = ldf(outp, i, isbf);
  for (long i = t; i < 262144; i += stride) ws[WS_GATW + i]= ldf(gatw, i, isbf);
  for (long i = t; i < 512;    i += stride) ws[WS_GAS + i] = ldf(gas, i, isbf);
  for (long i = t; i < 512;    i += stride) ws[WS_GAD + i] = ldf(gad, i, isbf);
  for (long i = t; i < 512;    i += stride) ws[WS_GAW + i] = ldf(gaw, i, isbf);
  for (long i = t; i < 1;      i += stride) ws[WS_GAB + i] = ldf(gab, i, isbf);
  for (long i = t; i < 512;    i += stride) ws[WS_S1 + i]  = ldf(s1, i, isbf);
  for (long i = t; i < 512;    i += stride) ws[WS_S2 + i]  = ldf(s2, i, isbf);
}

// ---------------- K2: pk_n = normalize(qk @ kp_w^T + b), f32 + bf16 copies ----------------
__global__ void k_pk(float* ws) {
  __shared__ float qk_s[8][256];
  __shared__ float pk_s[8][260];
  __shared__ float kw_s[32][260];
  __shared__ float red[8][32];
  __shared__ float invs[8];
  const int t = threadIdx.x, blk = blockIdx.x;
  for (int n = 0; n < 2; ++n) {
    int e4 = t + 256 * n;
    int r = e4 >> 6, j4 = e4 & 63;
    *(float4*)&qk_s[r][j4 * 4] =
      *(const float4*)&ws[WS_QK + (long)(blk * 8 + r) * 256 + j4 * 4];
  }
  const int il = t & 31, rg = t >> 5;
  for (int tile = 0; tile < 8; ++tile) {
    __syncthreads();
    for (int n = 0; n < 8; ++n) {
      int e4 = t + 256 * n;
      int ii = e4 >> 6, j4 = e4 & 63;
      *(float4*)&kw_s[ii][j4 * 4] =
        *(const float4*)&ws[WS_KPW + (long)(tile * 32 + ii) * 256 + j4 * 4];
    }
    __syncthreads();
    float acc = 0.f;
    for (int j = 0; j < 256; j += 4) {
      float4 a = *(const float4*)&qk_s[rg][j];
      float4 k4 = *(const float4*)&kw_s[il][j];
      acc += a.x * k4.x + a.y * k4.y + a.z * k4.z + a.w * k4.w;
    }
    pk_s[rg][tile * 32 + il] = acc + ws[WS_KPB + tile * 32 + il];
  }
  __syncthreads();
  {
    int r = t >> 5, c = t & 31;
    float s = 0.f;
    for (int q = 0; q < 8; ++q) { float v = pk_s[r][c + 32 * q]; s += v * v; }
    red[r][c] = s;
  }
  __syncthreads();
  if (t < 8) {
    float s = 0.f;
    for (int c = 0; c < 32; ++c) s += red[t][c];
    invs[t] = (float)(1.0 / fmax(sqrt((double)s), 1e-8));
  }
  __syncthreads();
  unsigned short* pkbf = (unsigned short*)(ws + WS_PKBF);
  for (int n = 0; n < 8; ++n) {
    int e = t + 256 * n;
    int r = e >> 8, i = e & 255;
    float pv = pk_s[r][i] * invs[r];
    long gi = (long)(blk * 8 + r) * 256 + i;
    ws[WS_PKN + gi] = pv;
    pkbf[gi] = f2bf(pv);
  }
}

// ---------------- K3a: ps projection via MFMA -> normalized bf16 ps rows ----------------
// 1563 blocks x 256 threads (4 waves), each block = 64 slots.
__global__ void __launch_bounds__(256) k_ps(const void* key_store, float* ws) {
  __shared__ unsigned short key_s[64 * 264];     // 33792 B (pad 8 bf16/row)
  const int isbf = *(const int*)ws;
  const int t = threadIdx.x;
  const long m_base = (long)blockIdx.x * 64;
  const unsigned short* kpwb = (const unsigned short*)(ws + WS_KPWB);
  unsigned short* psbf = (unsigned short*)(ws + WS_PSBF);

  if (isbf) {
    const unsigned short* kp = (const unsigned short*)key_store;
    for (int n = 0; n < 16; ++n) {
      int idx = t + 256 * n;                     // 4096 4-elem chunks
      int m = idx >> 6, j4 = idx & 63;
      uint2 u = make_uint2(0u, 0u);
      if (m_base + m < M_) u = *(const uint2*)&kp[(m_base + m) * 256 + j4 * 4];
      *(uint2*)&key_s[m * 264 + j4 * 4] = u;
    }
  } else {
    const float* kp = (const float*)key_store;
    for (int n = 0; n < 16; ++n) {
      int idx = t + 256 * n;
      int m = idx >> 6, j4 = idx & 63;
      uint2 u = make_uint2(0u, 0u);
      if (m_base + m < M_) {
        float4 v = *(const float4*)&kp[(m_base + m) * 256 + j4 * 4];
        u.x = (unsigned)f2bf(v.x) | ((unsigned)f2bf(v.y) << 16);
        u.y = (unsigned)f2bf(v.z) | ((unsigned)f2bf(v.w) << 16);
      }
      *(uint2*)&key_s[m * 264 + j4 * 4] = u;
    }
  }
  __syncthreads();

  const int lane = t & 63, wv = t >> 6;
  const int n16 = lane & 15, quad = lane >> 4;
  f32x4 acc[16] = {};
  const unsigned short* arow = &key_s[(wv * 16 + n16) * 264];
  for (int ks = 0; ks < 8; ++ks) {
    bf16x8 a = *(const bf16x8*)&arow[ks * 32 + quad * 8];
    const unsigned short* bp = kpwb + n16 * 256 + ks * 32 + quad * 8;
    #pragma unroll
    for (int it = 0; it < 16; ++it) {
      bf16x8 b = *(const bf16x8*)&bp[it * 4096];
      acc[it] = __builtin_amdgcn_mfma_f32_16x16x32_bf16(a, b, acc[it], 0, 0, 0);
    }
  }
  // bias + row norms (rows m = wv*16 + quad*4 + r; cols i = it*16 + n16)
  float ss[4] = {0.f, 0.f, 0.f, 0.f};
  #pragma unroll
  for (int it = 0; it < 16; ++it) {
    float bias = ws[WS_KPB + it * 16 + n16];
    acc[it][0] += bias; acc[it][1] += bias; acc[it][2] += bias; acc[it][3] += bias;
    #pragma unroll
    for (int r = 0; r < 4; ++r) ss[r] += acc[it][r] * acc[it][r];
  }
  #pragma unroll
  for (int r = 0; r < 4; ++r) {
    ss[r] += __shfl_xor(ss[r], 1); ss[r] += __shfl_xor(ss[r], 2);
    ss[r] += __shfl_xor(ss[r], 4); ss[r] += __shfl_xor(ss[r], 8);
    ss[r] = 1.0f / fmaxf(sqrtf(ss[r]), 1e-8f);
  }
  // normalized bf16 back into LDS (per-wave-disjoint rows; no barrier needed)
  #pragma unroll
  for (int it = 0; it < 16; ++it) {
    int col = it * 16 + n16;
    #pragma unroll
    for (int r = 0; r < 4; ++r)
      key_s[(wv * 16 + quad * 4 + r) * 264 + col] = f2bf(acc[it][r] * ss[r]);
  }
  __syncthreads();
  // coalesced store to ws psbf [m][256] bf16
  for (int n = 0; n < 8; ++n) {
    int idx = t + 256 * n;                       // 2048 8-elem chunks
    int m = idx >> 5, c8 = idx & 31;
    if (m_base + m < M_)
      *(uint4*)&psbf[(m_base + m) * 256 + c8 * 8] =
        *(const uint4*)&key_s[m * 264 + c8 * 8];
  }
}

// ---------------- K3b v4: transposed MFMA + in-register top-8 ----------------
// Block = 32 q-rows x 256 slots; 8 waves, each wave = all 32 q x 32 slots.
// Transposed mfma(ps, pk): C col = q (lane n16), row = s (quad*4+reg) -> each
// lane holds 8 s-values of ONE q-row in registers. Top-8 per q is built fully
// in registers (insert-8 + 2 quad shfl-merges + 3 cross-wave shfl-merges) —
// no 67KB sim LDS, no serial 128-iter scan, barriers 4->2.
// LDS 33.3KB + VGPR<=64 -> 4 blocks/CU = 32 waves/CU (occupancy cap).
// Candidate output format, CPR2 and k_topk are UNCHANGED.

// compare-exchange on (tv,ti) desc by (v desc, idx asc)
#define CE8(i, j) { \
  bool g_ = (tv[i] > tv[j]) || (tv[i] == tv[j] && ti[i] < ti[j]); \
  float va_ = g_ ? tv[i] : tv[j]; float vb_ = g_ ? tv[j] : tv[i]; \
  int ia_ = g_ ? ti[i] : ti[j]; int ib_ = g_ ? ti[j] : ti[i]; \
  tv[i] = va_; tv[j] = vb_; ti[i] = ia_; ti[j] = ib_; }

// merge my sorted-8 desc list with lane^D's: keep exact top-8, re-sort desc
#define MERGE_XOR(D) { \
  float pv[8]; int pi[8]; \
  _Pragma("unroll") \
  for (int k_ = 0; k_ < 8; ++k_) { pv[k_] = __shfl_xor(tv[k_], D); pi[k_] = __shfl_xor(ti[k_], D); } \
  _Pragma("unroll") \
  for (int k_ = 0; k_ < 8; ++k_) { \
    bool g_ = (tv[k_] > pv[7 - k_]) || (tv[k_] == pv[7 - k_] && ti[k_] < pi[7 - k_]); \
    tv[k_] = g_ ? tv[k_] : pv[7 - k_]; ti[k_] = g_ ? ti[k_] : pi[7 - k_]; } \
  CE8(0,4) CE8(1,5) CE8(2,6) CE8(3,7) \
  CE8(0,2) CE8(1,3) CE8(4,6) CE8(5,7) \
  CE8(0,1) CE8(2,3) CE8(4,5) CE8(6,7) }

__global__ void __launch_bounds__(512, 8) k_sim(float* ws) {
  __shared__ __align__(16) unsigned short pk_s[32 * 264];   // 16896 B
  __shared__ float candv[8][32][8];                         // 8192 B
  __shared__ int   candi[8][32][8];                         // 8192 B

  const int t = threadIdx.x;
  // XCD-affine: grid = 49*128; the 16 qtile-blocks of a stile share bid&7
  const int bid = blockIdx.x;
  const int qtile = (bid >> 3) & 15;
  const int stile = (bid >> 7) * 8 + (bid & 7);
  if (stile >= NST) return;                     // 16 dead blocks (stile 391)
  const int qbase = qtile * 32;
  const long sbase = (long)stile * 256;
  const unsigned short* pkbf = (const unsigned short*)(ws + WS_PKBF);
  const unsigned short* psbf = (const unsigned short*)(ws + WS_PSBF);

  // stage pk tile [32][256] -> [32][264]
  for (int n = 0; n < 2; ++n) {
    int idx = t + 512 * n;                      // 1024 8-elem chunks
    int m = idx >> 5, c8 = idx & 31;
    *(uint4*)&pk_s[m * 264 + c8 * 8] =
      *(const uint4*)&pkbf[(long)(qbase + m) * 256 + c8 * 8];
  }
  __syncthreads();

  const int lane = t & 63, wv = t >> 6;
  const int n16 = lane & 15, quad = lane >> 4;
  const int sw = wv * 32;                       // wave's slot offset in chunk
  f32x4 acc[2][2] = {};                         // [sf][qf]

  // A (ps) row pointers, 2 s-fragments; clamp OOB rows (excluded later)
  const unsigned short* ap0;
  const unsigned short* ap1;
  {
    long r0 = sbase + sw + n16;       if (r0 >= M_) r0 = 0;
    long r1 = sbase + sw + 16 + n16;  if (r1 >= M_) r1 = 0;
    ap0 = psbf + r0 * 256 + quad * 8;
    ap1 = psbf + r1 * 256 + quad * 8;
  }
  const unsigned short* bq0 = &pk_s[(n16) * 264 + quad * 8];
  const unsigned short* bq1 = &pk_s[(16 + n16) * 264 + quad * 8];

  #pragma unroll
  for (int ks = 0; ks < 8; ++ks) {
    bf16x8 a0 = *(const bf16x8*)&ap0[ks * 32];
    bf16x8 a1 = *(const bf16x8*)&ap1[ks * 32];
    bf16x8 b0 = *(const bf16x8*)&bq0[ks * 32];
    bf16x8 b1 = *(const bf16x8*)&bq1[ks * 32];
    acc[0][0] = __builtin_amdgcn_mfma_f32_16x16x32_bf16(a0, b0, acc[0][0], 0, 0, 0);
    acc[0][1] = __builtin_amdgcn_mfma_f32_16x16x32_bf16(a0, b1, acc[0][1], 0, 0, 0);
    acc[1][0] = __builtin_amdgcn_mfma_f32_16x16x32_bf16(a1, b0, acc[1][0], 0, 0, 0);
    acc[1][1] = __builtin_amdgcn_mfma_f32_16x16x32_bf16(a1, b1, acc[1][1], 0, 0, 0);
  }

  // per-wave top-8 over its 32 s, for each of 32 q (qf x n16)
  const int sl0 = (int)sbase + sw + quad * 4;   // lane's s base (sf=0,r=0)
  #pragma unroll
  for (int qf = 0; qf < 2; ++qf) {
    float tv[8]; int ti[8];
    #pragma unroll
    for (int k = 0; k < 8; ++k) { tv[k] = -3.0e38f; ti[k] = 0x7FFFFFFF; }
    #pragma unroll
    for (int sf = 0; sf < 2; ++sf) {
      #pragma unroll
      for (int r = 0; r < 4; ++r) {             // lane's s ascending
        int s = sl0 + sf * 16 + r;
        float v = (s < M_) ? acc[sf][qf][r] : -3.0e38f;
        if (v > tv[7]) {
          bool placed = false;
          #pragma unroll
          for (int qq = 7; qq >= 1; --qq) {
            if (!placed) {
              if (v > tv[qq - 1]) { tv[qq] = tv[qq - 1]; ti[qq] = ti[qq - 1]; }
              else { tv[qq] = v; ti[qq] = s; placed = true; }
            }
          }
          if (!placed) { tv[0] = v; ti[0] = s; }
        }
      }
    }
    MERGE_XOR(16)                               // quads {0,1} / {2,3}
    MERGE_XOR(32)                               // all 4 quads -> top-8 of 32 s
    if (quad == 0) {
      #pragma unroll
      for (int k = 0; k < 8; ++k) {
        candv[wv][qf * 16 + n16][k] = tv[k];
        candi[wv][qf * 16 + n16][k] = ti[k];
      }
    }
  }
  __syncthreads();

  // cross-wave merge: 8 sorted lists per q -> exact top-8 of 256 slots
  if (t < 256) {
    int q = t >> 3, j = t & 7;
    float tv[8]; int ti[8];
    #pragma unroll
    for (int k = 0; k < 8; ++k) { tv[k] = candv[j][q][k]; ti[k] = candi[j][q][k]; }
    MERGE_XOR(1)
    MERGE_XOR(2)
    MERGE_XOR(4)
    if (j == 0) {
      float* cv = ws + WS_CANDV;
      int* ci = (int*)(ws + WS_CANDI);
      long ob = (long)(qbase + q) * CPR2 + (long)stile * 8;
      #pragma unroll
      for (int k = 0; k < 8; ++k) { cv[ob + k] = tv[k]; ci[ob + k] = ti[k]; }
    }
  }
}

// ---------------- K4: per-row merge -> top16 -> f64 rescore -> top8 ----------------
__global__ void k_topk(const void* key_store, const void* idx_store,
                       float* ws, void* dout) {
  __shared__ unsigned long long keys[256 * 16];
  __shared__ unsigned long long redk[256];
  __shared__ unsigned long long res[16];
  __shared__ int cidx[16];
  __shared__ double rv[16];
  const int isbf = *(const int*)ws;
  const int t = threadIdx.x, b = blockIdx.x;
  unsigned long long* ml = &keys[t * 16];
  #pragma unroll
  for (int q = 0; q < 16; ++q) ml[q] = 0ull;
  const float* cv = ws + WS_CANDV;
  const int* ci = (const int*)(ws + WS_CANDI);
  long base = (long)b * CPR2;
  for (int cc = t; cc < CPR2; cc += 256) {
    float v = cv[base + cc];
    unsigned id = (unsigned)ci[base + cc];
    unsigned bb = __float_as_uint(v);
    unsigned o = (bb & 0x80000000u) ? ~bb : (bb | 0x80000000u);
    unsigned long long key = ((unsigned long long)o << 32) |
                             (unsigned long long)(0xFFFFFFFFu - id);
    if (key > ml[15]) {
      int q = 15;
      while (q > 0 && key > ml[q - 1]) { ml[q] = ml[q - 1]; --q; }
      ml[q] = key;
    }
  }
  __syncthreads();
  int h = 0;
  for (int r = 0; r < 16; ++r) {
    redk[t] = (h < 16) ? ml[h] : 0ull;
    __syncthreads();
    for (int s = 128; s > 0; s >>= 1) {
      if (t < s) { if (redk[t + s] > redk[t]) redk[t] = redk[t + s]; }
      __syncthreads();
    }
    unsigned long long win = redk[0];
    if (h < 16 && ml[h] == win) ++h;
    if (t == 0) res[r] = win;
    __syncthreads();
  }
  if (t < 16) cidx[t] = (int)(0xFFFFFFFFu - (unsigned)(res[t] & 0xFFFFFFFFu));
  __syncthreads();
  // f64 rescore of 16 candidates (16 threads per candidate)
  {
    int cand = t >> 4, p = t & 15;
    long m = (long)cidx[cand];
    double dp = 0.0, nr = 0.0;
    for (int ii = 0; ii < 16; ++ii) {
      int i = p * 16 + ii;
      double s = (double)ws[WS_KPB + i];
      const float* wrow = ws + WS_KPW + (long)i * 256;
      if (isbf) {
        const unsigned short* kr = (const unsigned short*)key_store + m * 256;
        for (int j = 0; j < 256; ++j)
          s += (double)__uint_as_float((unsigned)kr[j] << 16) * (double)wrow[j];
      } else {
        const float* kr = (const float*)key_store + m * 256;
        for (int j = 0; j < 256; ++j)
          s += (double)kr[j] * (double)wrow[j];
      }
      dp += s * (double)ws[WS_PKN + (long)b * 256 + i];
      nr += s * s;
    }
    dp += __shfl_xor(dp, 1); nr += __shfl_xor(nr, 1);
    dp += __shfl_xor(dp, 2); nr += __shfl_xor(nr, 2);
    dp += __shfl_xor(dp, 4); nr += __shfl_xor(nr, 4);
    dp += __shfl_xor(dp, 8); nr += __shfl_xor(nr, 8);
    if (p == 0) rv[cand] = dp / fmax(sqrt(nr), 1e-8);
  }
  __syncthreads();
  if (t == 0) {
    int ordr[16];
    for (int q = 0; q < 16; ++q) ordr[q] = q;
    for (int a = 0; a < 8; ++a) {
      int best = a;
      for (int x = a + 1; x < 16; ++x) {
        int xi = ordr[x], bi = ordr[best];
        if (rv[xi] > rv[bi] || (rv[xi] == rv[bi] && cidx[xi] < cidx[bi])) best = x;
      }
      int tmp = ordr[a]; ordr[a] = ordr[best]; ordr[best] = tmp;
    }
    int* seli = (int*)(ws + WS_SELI);
    for (int r = 0; r < 8; ++r) {
      int m = cidx[ordr[r]];
      stf(dout, OUT_IDX + b * 8 + r, (float)m, isbf);
      stf(dout, OUT_SIMV + b * 8 + r, (float)rv[ordr[r]], isbf);
      stf(dout, OUT_SELIDX + b * 8 + r, ldf(idx_store, m, isbf), isbf);
      seli[b * 8 + r] = m;
    }
  }
}

// ---------------- K5: GAT compose + count-sketch + circular conv ----------------
__global__ void k_compose(const void* value_store, const int* h1, const int* h2,
                          float* ws, void* dout) {
  __shared__ float feats[9][512];
  __shared__ float Wh[9][512];
  __shared__ float g0[9][8];
  __shared__ float sd_[2][9][8];
  __shared__ float psi1[512], psi2[512], pooled[512];
  __shared__ float wk[9];
  __shared__ float redz[40];
  __shared__ int sel[8];
  const int isbf = *(const int*)ws;
  const int t = threadIdx.x, b = blockIdx.x;
  if (t < 8) sel[t] = ((const int*)(ws + WS_SELI))[b * 8 + t];
  feats[0][t]       = ws[WS_OUT + (long)b * 512 + t];
  feats[0][t + 256] = ws[WS_OUT + (long)b * 512 + t + 256];
  __syncthreads();
  for (int n = 0; n < 16; ++n) {
    int e = t + 256 * n;
    int r = e >> 9, d = e & 511;
    feats[1 + r][d] = ldf(value_store, (long)sel[r] * 512 + d, isbf);
  }
  __syncthreads();
  {
    const int he0 = t, he1 = t + 256;
    float a0[9] = {}, a1[9] = {};
    const float* gw = ws + WS_GATW;
    for (int d = 0; d < 512; ++d) {
      float w0 = gw[(long)d * 512 + he0];
      float w1 = gw[(long)d * 512 + he1];
      #pragma unroll
      for (int k = 0; k < 9; ++k) {
        float a = feats[k][d];
        a0[k] += a * w0;
        a1[k] += a * w1;
      }
    }
    #pragma unroll
    for (int k = 0; k < 9; ++k) { Wh[k][he0] = a0[k]; Wh[k][he1] = a1[k]; }
  }
  __syncthreads();
  if (t < 144) {
    int k = t >> 4, rem = t & 15, hh = rem >> 1, sdx = rem & 1;
    const float* av = ws + (sdx ? WS_GAD : WS_GAS) + hh * 64;
    float s = 0.f;
    for (int e = 0; e < 64; ++e) s += Wh[k][hh * 64 + e] * av[e];
    sd_[sdx][k][hh] = s;
  }
  __syncthreads();
  if (t < 8) {
    float L[9], mx = -3e38f;
    for (int j = 0; j < 9; ++j) {
      float x = sd_[0][0][t] + sd_[1][j][t];
      L[j] = x > 0.f ? x : 0.2f * x;
      mx = fmaxf(mx, L[j]);
    }
    float ssum = 0.f;
    for (int j = 0; j < 9; ++j) { L[j] = expf(L[j] - mx); ssum += L[j]; }
    for (int j = 0; j < 9; ++j) g0[j][t] = L[j] / ssum;
  }
  __syncthreads();
  for (int n = 0; n < 3; ++n) {
    int e = t + 256 * n;
    if (e < 648) {
      int i = e / 72, rem = e % 72, j = rem >> 3, hh = rem & 7;
      float v = (i == 0) ? g0[j][hh] : ((i == j) ? 1.0f : 0.0f);
      stf(dout, OUT_GATT + (long)b * 648 + e, v, isbf);
    }
  }
  __syncthreads();
  #pragma unroll
  for (int i = 0; i < 9; ++i) {
    for (int half = 0; half < 2; ++half) {
      int d = t + half * 256;
      float x;
      if (i == 0) {
        int hh = d >> 6;
        x = 0.f;
        #pragma unroll
        for (int j = 0; j < 9; ++j) x += g0[j][hh] * Wh[j][d];
      } else x = Wh[i][d];
      feats[i][d] = x > 0.f ? x : expm1f(x);
    }
  }
  __syncthreads();
  {
    float part[9];
    const float* aw = ws + WS_GAW;
    #pragma unroll
    for (int k = 0; k < 9; ++k)
      part[k] = feats[k][t] * aw[t] + feats[k][t + 256] * aw[t + 256];
    #pragma unroll
    for (int k = 0; k < 9; ++k) {
      float s = part[k];
      s += __shfl_xor(s, 1);  s += __shfl_xor(s, 2);  s += __shfl_xor(s, 4);
      s += __shfl_xor(s, 8);  s += __shfl_xor(s, 16); s += __shfl_xor(s, 32);
      if ((t & 63) == 0) redz[(t >> 6) * 9 + k] = s;
    }
  }
  __syncthreads();
  if (t == 0) {
    float l[9], mx = -3e38f;
    for (int k = 0; k < 9; ++k) {
      l[k] = redz[k] + redz[9 + k] + redz[18 + k] + redz[27 + k] + ws[WS_GAB];
      mx = fmaxf(mx, l[k]);
    }
    float ssum = 0.f;
    for (int k = 0; k < 9; ++k) { l[k] = expf(l[k] - mx); ssum += l[k]; }
    for (int k = 0; k < 9; ++k) wk[k] = l[k] / ssum;
  }
  __syncthreads();
  for (int half = 0; half < 2; ++half) {
    int d = t + half * 256;
    float s = 0.f;
    #pragma unroll
    for (int k = 0; k < 9; ++k) s += wk[k] * feats[k][d];
    pooled[d] = s;
    psi1[d] = 0.f; psi2[d] = 0.f;
  }
  __syncthreads();
  for (int half = 0; half < 2; ++half) {
    int j = t + half * 256;
    atomicAdd(&psi1[h1[j]], ws[WS_OUT + (long)b * 512 + j] * ws[WS_S1 + j]);
    atomicAdd(&psi2[h2[j]], pooled[j] * ws[WS_S2 + j]);
  }
  __syncthreads();
  for (int half = 0; half < 2; ++half) {
    int tt = t + half * 256;
    float s = 0.f;
    for (int j = 0; j < 512; ++j) s += psi1[j] * psi2[(tt - j) & 511];
    stf(dout, OUT_COMPOSED + (long)b * 1024 + tt, s, isbf);
    stf(dout, OUT_COMPOSED + (long)b * 1024 + 512 + tt,
        ws[WS_OUT + (long)b * 512 + tt], isbf);
  }
}

// ---------------- launch ----------------
extern "C" void kernel_launch(void* const* d_in, const int* in_sizes, int n_in,
                              void* d_out, int out_size, void* d_ws, size_t ws_size,
                              hipStream_t stream) {
  float* ws = (float*)d_ws;
  k_detect<<<1, 64, 0, stream>>>((const unsigned*)d_in[15], (int*)d_ws);
  k_prep<<<512, 256, 0, stream>>>(d_in[1], d_in[6], d_in[7], d_in[0], d_in[8],
                                  d_in[9], d_in[10], d_in[11], d_in[12],
                                  d_in[15], d_in[16], ws);
  k_pk<<<64, 256, 0, stream>>>(ws);
  k_ps<<<NPS, 256, 0, stream>>>(d_in[3], ws);
  // v4: 16 qtiles x 391 stiles, XCD-affine; 49 groups x 128 = 6272 blocks
  k_sim<<<49 * 128, 512, 0, stream>>>(ws);
  k_topk<<<512, 256, 0, stream>>>(d_in[3], d_in[5], ws, d_out);
  k_compose<<<512, 256, 0, stream>>>(d_in[4], (const int*)d_in[13],
                                     (const int*)d_in[14], ws, d_out);
}

// Round 6
// 796.105 us; speedup vs baseline: 1.7573x; 1.3254x over previous
//
#include <hip/hip_runtime.h>
#include <hip/hip_bf16.h>

// ---------------- problem constants ----------------
#define B_      512
#define KD_     256
#define VD_     512
#define M_      100000
#define NPS     1563        // ceil(100000/64) blocks for k_ps
#define NST     391         // ceil(100000/256) slot tiles for k_sim
#define CPR2    (NST*8)     // candidates per row = 3128

// output element offsets (concatenated tuple, flat)
#define OUT_COMPOSED 0L
#define OUT_IDX      524288L
#define OUT_SIMV     528384L
#define OUT_GATT     532480L
#define OUT_SELIDX   864256L

typedef __attribute__((ext_vector_type(8))) short bf16x8;
typedef __attribute__((ext_vector_type(4))) float f32x4;

// workspace float-element offsets (keep 16-float alignment for bf16 regions)
static constexpr long WS_FLAG = 0;
static constexpr long WS_QK   = 64;                  // 131072
static constexpr long WS_KPW  = WS_QK + 131072;      // 65536 (kp_w natural [i][j], f32)
static constexpr long WS_KPB  = WS_KPW + 65536;      // 256
static constexpr long WS_OUT  = WS_KPB + 256;        // 262144
static constexpr long WS_GATW = WS_OUT + 262144;     // 262144
static constexpr long WS_GAS  = WS_GATW + 262144;    // 512
static constexpr long WS_GAD  = WS_GAS + 512;        // 512
static constexpr long WS_GAW  = WS_GAD + 512;        // 512
static constexpr long WS_GAB  = WS_GAW + 512;        // 64
static constexpr long WS_S1   = WS_GAB + 64;         // 512
static constexpr long WS_S2   = WS_S1 + 512;         // 512
static constexpr long WS_PKN  = WS_S2 + 512;         // 131072 (pk normalized f32)
static constexpr long WS_SELI = WS_PKN + 131072;     // int[512*8]
static constexpr long WS_PKBF = WS_SELI + 4096;      // bf16[512*256]  = 65536 floats
static constexpr long WS_KPWB = WS_PKBF + 65536;     // bf16[256*256]  = 32768 floats
static constexpr long WS_PSBF = WS_KPWB + 32768;     // bf16[100000*256] = 12800000 floats
static constexpr long WS_CANDV= WS_PSBF + 12800000;  // float[512*CPR2]
static constexpr long WS_CANDI= WS_CANDV + (long)CPR2 * B_; // int[512*CPR2]

// ---------------- helpers ----------------
__device__ __forceinline__ float ldf(const void* p, long i, int isbf) {
  if (isbf) {
    unsigned short u = ((const unsigned short*)p)[i];
    return __uint_as_float(((unsigned)u) << 16);
  }
  return ((const float*)p)[i];
}
__device__ __forceinline__ void stf(void* p, long i, float v, int isbf) {
  if (isbf) ((__hip_bfloat16*)p)[i] = __float2bfloat16(v);
  else ((float*)p)[i] = v;
}
__device__ __forceinline__ unsigned short f2bf(float f) {
  union { float f; unsigned u; } x; x.f = f;
  unsigned r = x.u + 0x7FFFu + ((x.u >> 16) & 1u);   // RNE
  return (unsigned short)(r >> 16);
}

// ---------------- K0: detect input dtype ----------------
__global__ void k_detect(const unsigned* s1, int* flag) {
  if (threadIdx.x == 0) {
    unsigned w = s1[0];
    *flag = ((w & 0x7FFF7FFFu) == 0x3F803F80u) ? 1 : 0;
  }
}

// ---------------- K1: stage constants as f32 (+bf16 kp_w) in ws ----------------
__global__ void k_prep(const void* qk, const void* kpw, const void* kpb,
                       const void* outp, const void* gatw, const void* gas,
                       const void* gad, const void* gaw, const void* gab,
                       const void* s1, const void* s2, float* ws) {
  const int isbf = *(const int*)ws;
  long t = (long)blockIdx.x * blockDim.x + threadIdx.x;
  long stride = (long)gridDim.x * blockDim.x;
  unsigned short* kpwb = (unsigned short*)(ws + WS_KPWB);
  for (long i = t; i < 131072; i += stride) ws[WS_QK + i]  = ldf(qk, i, isbf);
  for (long i = t; i < 65536;  i += stride) {
    float v = ldf(kpw, i, isbf);
    ws[WS_KPW + i] = v;
    kpwb[i] = f2bf(v);
  }
  for (long i = t; i < 256;    i += stride) ws[WS_KPB + i] = ldf(kpb, i, isbf);
  for (long i = t; i < 262144; i += stride) ws[WS_OUT + i] = ldf(outp, i, isbf);
  for (long i = t; i < 262144; i += stride) ws[WS_GATW + i]= ldf(gatw, i, isbf);
  for (long i = t; i < 512;    i += stride) ws[WS_GAS + i] = ldf(gas, i, isbf);
  for (long i = t; i < 512;    i += stride) ws[WS_GAD + i] = ldf(gad, i, isbf);
  for (long i = t; i < 512;    i += stride) ws[WS_GAW + i] = ldf(gaw, i, isbf);
  for (long i = t; i < 1;      i += stride) ws[WS_GAB + i] = ldf(gab, i, isbf);
  for (long i = t; i < 512;    i += stride) ws[WS_S1 + i]  = ldf(s1, i, isbf);
  for (long i = t; i < 512;    i += stride) ws[WS_S2 + i]  = ldf(s2, i, isbf);
}

// ---------------- K2: pk_n = normalize(qk @ kp_w^T + b), f32 + bf16 copies ----------------
__global__ void k_pk(float* ws) {
  __shared__ float qk_s[8][256];
  __shared__ float pk_s[8][260];
  __shared__ float kw_s[32][260];
  __shared__ float red[8][32];
  __shared__ float invs[8];
  const int t = threadIdx.x, blk = blockIdx.x;
  for (int n = 0; n < 2; ++n) {
    int e4 = t + 256 * n;
    int r = e4 >> 6, j4 = e4 & 63;
    *(float4*)&qk_s[r][j4 * 4] =
      *(const float4*)&ws[WS_QK + (long)(blk * 8 + r) * 256 + j4 * 4];
  }
  const int il = t & 31, rg = t >> 5;
  for (int tile = 0; tile < 8; ++tile) {
    __syncthreads();
    for (int n = 0; n < 8; ++n) {
      int e4 = t + 256 * n;
      int ii = e4 >> 6, j4 = e4 & 63;
      *(float4*)&kw_s[ii][j4 * 4] =
        *(const float4*)&ws[WS_KPW + (long)(tile * 32 + ii) * 256 + j4 * 4];
    }
    __syncthreads();
    float acc = 0.f;
    for (int j = 0; j < 256; j += 4) {
      float4 a = *(const float4*)&qk_s[rg][j];
      float4 k4 = *(const float4*)&kw_s[il][j];
      acc += a.x * k4.x + a.y * k4.y + a.z * k4.z + a.w * k4.w;
    }
    pk_s[rg][tile * 32 + il] = acc + ws[WS_KPB + tile * 32 + il];
  }
  __syncthreads();
  {
    int r = t >> 5, c = t & 31;
    float s = 0.f;
    for (int q = 0; q < 8; ++q) { float v = pk_s[r][c + 32 * q]; s += v * v; }
    red[r][c] = s;
  }
  __syncthreads();
  if (t < 8) {
    float s = 0.f;
    for (int c = 0; c < 32; ++c) s += red[t][c];
    invs[t] = (float)(1.0 / fmax(sqrt((double)s), 1e-8));
  }
  __syncthreads();
  unsigned short* pkbf = (unsigned short*)(ws + WS_PKBF);
  for (int n = 0; n < 8; ++n) {
    int e = t + 256 * n;
    int r = e >> 8, i = e & 255;
    float pv = pk_s[r][i] * invs[r];
    long gi = (long)(blk * 8 + r) * 256 + i;
    ws[WS_PKN + gi] = pv;
    pkbf[gi] = f2bf(pv);
  }
}

// ---------------- K3a: ps projection via MFMA -> normalized bf16 ps rows ----------------
// 1563 blocks x 256 threads (4 waves), each block = 64 slots.
__global__ void __launch_bounds__(256) k_ps(const void* key_store, float* ws) {
  __shared__ unsigned short key_s[64 * 264];     // 33792 B (pad 8 bf16/row)
  const int isbf = *(const int*)ws;
  const int t = threadIdx.x;
  const long m_base = (long)blockIdx.x * 64;
  const unsigned short* kpwb = (const unsigned short*)(ws + WS_KPWB);
  unsigned short* psbf = (unsigned short*)(ws + WS_PSBF);

  if (isbf) {
    const unsigned short* kp = (const unsigned short*)key_store;
    for (int n = 0; n < 16; ++n) {
      int idx = t + 256 * n;                     // 4096 4-elem chunks
      int m = idx >> 6, j4 = idx & 63;
      uint2 u = make_uint2(0u, 0u);
      if (m_base + m < M_) u = *(const uint2*)&kp[(m_base + m) * 256 + j4 * 4];
      *(uint2*)&key_s[m * 264 + j4 * 4] = u;
    }
  } else {
    const float* kp = (const float*)key_store;
    for (int n = 0; n < 16; ++n) {
      int idx = t + 256 * n;
      int m = idx >> 6, j4 = idx & 63;
      uint2 u = make_uint2(0u, 0u);
      if (m_base + m < M_) {
        float4 v = *(const float4*)&kp[(m_base + m) * 256 + j4 * 4];
        u.x = (unsigned)f2bf(v.x) | ((unsigned)f2bf(v.y) << 16);
        u.y = (unsigned)f2bf(v.z) | ((unsigned)f2bf(v.w) << 16);
      }
      *(uint2*)&key_s[m * 264 + j4 * 4] = u;
    }
  }
  __syncthreads();

  const int lane = t & 63, wv = t >> 6;
  const int n16 = lane & 15, quad = lane >> 4;
  f32x4 acc[16] = {};
  const unsigned short* arow = &key_s[(wv * 16 + n16) * 264];
  for (int ks = 0; ks < 8; ++ks) {
    bf16x8 a = *(const bf16x8*)&arow[ks * 32 + quad * 8];
    const unsigned short* bp = kpwb + n16 * 256 + ks * 32 + quad * 8;
    #pragma unroll
    for (int it = 0; it < 16; ++it) {
      bf16x8 b = *(const bf16x8*)&bp[it * 4096];
      acc[it] = __builtin_amdgcn_mfma_f32_16x16x32_bf16(a, b, acc[it], 0, 0, 0);
    }
  }
  // bias + row norms (rows m = wv*16 + quad*4 + r; cols i = it*16 + n16)
  float ss[4] = {0.f, 0.f, 0.f, 0.f};
  #pragma unroll
  for (int it = 0; it < 16; ++it) {
    float bias = ws[WS_KPB + it * 16 + n16];
    acc[it][0] += bias; acc[it][1] += bias; acc[it][2] += bias; acc[it][3] += bias;
    #pragma unroll
    for (int r = 0; r < 4; ++r) ss[r] += acc[it][r] * acc[it][r];
  }
  #pragma unroll
  for (int r = 0; r < 4; ++r) {
    ss[r] += __shfl_xor(ss[r], 1); ss[r] += __shfl_xor(ss[r], 2);
    ss[r] += __shfl_xor(ss[r], 4); ss[r] += __shfl_xor(ss[r], 8);
    ss[r] = 1.0f / fmaxf(sqrtf(ss[r]), 1e-8f);
  }
  // normalized bf16 back into LDS (per-wave-disjoint rows; no barrier needed)
  #pragma unroll
  for (int it = 0; it < 16; ++it) {
    int col = it * 16 + n16;
    #pragma unroll
    for (int r = 0; r < 4; ++r)
      key_s[(wv * 16 + quad * 4 + r) * 264 + col] = f2bf(acc[it][r] * ss[r]);
  }
  __syncthreads();
  // coalesced store to ws psbf [m][256] bf16
  for (int n = 0; n < 8; ++n) {
    int idx = t + 256 * n;                       // 2048 8-elem chunks
    int m = idx >> 5, c8 = idx & 31;
    if (m_base + m < M_)
      *(uint4*)&psbf[(m_base + m) * 256 + c8 * 8] =
        *(const uint4*)&key_s[m * 264 + c8 * 8];
  }
}

// ---------------- K3b v4: transposed MFMA + in-register top-8 ----------------
// Block = 32 q-rows x 256 slots; 8 waves, each wave = all 32 q x 32 slots.
// Transposed mfma(ps, pk): C col = q (lane n16), row = s (quad*4+reg) -> each
// lane holds 8 s-values of ONE q-row in registers. Top-8 per q is built fully
// in registers (insert-8 + 2 quad shfl-merges + 3 cross-wave shfl-merges).

// compare-exchange on (tv,ti) desc by (v desc, idx asc)
#define CE8(i, j) { \
  bool g_ = (tv[i] > tv[j]) || (tv[i] == tv[j] && ti[i] < ti[j]); \
  float va_ = g_ ? tv[i] : tv[j]; float vb_ = g_ ? tv[j] : tv[i]; \
  int ia_ = g_ ? ti[i] : ti[j]; int ib_ = g_ ? ti[j] : ti[i]; \
  tv[i] = va_; tv[j] = vb_; ti[i] = ia_; ti[j] = ib_; }

// merge my sorted-8 desc list with lane^D's: keep exact top-8, re-sort desc
#define MERGE_XOR(D) { \
  float pv[8]; int pi[8]; \
  _Pragma("unroll") \
  for (int k_ = 0; k_ < 8; ++k_) { pv[k_] = __shfl_xor(tv[k_], D); pi[k_] = __shfl_xor(ti[k_], D); } \
  _Pragma("unroll") \
  for (int k_ = 0; k_ < 8; ++k_) { \
    bool g_ = (tv[k_] > pv[7 - k_]) || (tv[k_] == pv[7 - k_] && ti[k_] < pi[7 - k_]); \
    tv[k_] = g_ ? tv[k_] : pv[7 - k_]; ti[k_] = g_ ? ti[k_] : pi[7 - k_]; } \
  CE8(0,4) CE8(1,5) CE8(2,6) CE8(3,7) \
  CE8(0,2) CE8(1,3) CE8(4,6) CE8(5,7) \
  CE8(0,1) CE8(2,3) CE8(4,5) CE8(6,7) }

__global__ void __launch_bounds__(512, 8) k_sim(float* ws) {
  __shared__ __align__(16) unsigned short pk_s[32 * 264];   // 16896 B
  __shared__ float candv[8][32][8];                         // 8192 B
  __shared__ int   candi[8][32][8];                         // 8192 B

  const int t = threadIdx.x;
  // XCD-affine: grid = 49*128; the 16 qtile-blocks of a stile share bid&7
  const int bid = blockIdx.x;
  const int qtile = (bid >> 3) & 15;
  const int stile = (bid >> 7) * 8 + (bid & 7);
  if (stile >= NST) return;                     // 16 dead blocks (stile 391)
  const int qbase = qtile * 32;
  const long sbase = (long)stile * 256;
  const unsigned short* pkbf = (const unsigned short*)(ws + WS_PKBF);
  const unsigned short* psbf = (const unsigned short*)(ws + WS_PSBF);

  // stage pk tile [32][256] -> [32][264]
  for (int n = 0; n < 2; ++n) {
    int idx = t + 512 * n;                      // 1024 8-elem chunks
    int m = idx >> 5, c8 = idx & 31;
    *(uint4*)&pk_s[m * 264 + c8 * 8] =
      *(const uint4*)&pkbf[(long)(qbase + m) * 256 + c8 * 8];
  }
  __syncthreads();

  const int lane = t & 63, wv = t >> 6;
  const int n16 = lane & 15, quad = lane >> 4;
  const int sw = wv * 32;                       // wave's slot offset in chunk
  f32x4 acc[2][2] = {};                         // [sf][qf]

  // A (ps) row pointers, 2 s-fragments; clamp OOB rows (excluded later)
  const unsigned short* ap0;
  const unsigned short* ap1;
  {
    long r0 = sbase + sw + n16;       if (r0 >= M_) r0 = 0;
    long r1 = sbase + sw + 16 + n16;  if (r1 >= M_) r1 = 0;
    ap0 = psbf + r0 * 256 + quad * 8;
    ap1 = psbf + r1 * 256 + quad * 8;
  }
  const unsigned short* bq0 = &pk_s[(n16) * 264 + quad * 8];
  const unsigned short* bq1 = &pk_s[(16 + n16) * 264 + quad * 8];

  #pragma unroll
  for (int ks = 0; ks < 8; ++ks) {
    bf16x8 a0 = *(const bf16x8*)&ap0[ks * 32];
    bf16x8 a1 = *(const bf16x8*)&ap1[ks * 32];
    bf16x8 b0 = *(const bf16x8*)&bq0[ks * 32];
    bf16x8 b1 = *(const bf16x8*)&bq1[ks * 32];
    acc[0][0] = __builtin_amdgcn_mfma_f32_16x16x32_bf16(a0, b0, acc[0][0], 0, 0, 0);
    acc[0][1] = __builtin_amdgcn_mfma_f32_16x16x32_bf16(a0, b1, acc[0][1], 0, 0, 0);
    acc[1][0] = __builtin_amdgcn_mfma_f32_16x16x32_bf16(a1, b0, acc[1][0], 0, 0, 0);
    acc[1][1] = __builtin_amdgcn_mfma_f32_16x16x32_bf16(a1, b1, acc[1][1], 0, 0, 0);
  }

  // per-wave top-8 over its 32 s, for each of 32 q (qf x n16)
  const int sl0 = (int)sbase + sw + quad * 4;   // lane's s base (sf=0,r=0)
  #pragma unroll
  for (int qf = 0; qf < 2; ++qf) {
    float tv[8]; int ti[8];
    #pragma unroll
    for (int k = 0; k < 8; ++k) { tv[k] = -3.0e38f; ti[k] = 0x7FFFFFFF; }
    #pragma unroll
    for (int sf = 0; sf < 2; ++sf) {
      #pragma unroll
      for (int r = 0; r < 4; ++r) {             // lane's s ascending
        int s = sl0 + sf * 16 + r;
        float v = (s < M_) ? acc[sf][qf][r] : -3.0e38f;
        if (v > tv[7]) {
          bool placed = false;
          #pragma unroll
          for (int qq = 7; qq >= 1; --qq) {
            if (!placed) {
              if (v > tv[qq - 1]) { tv[qq] = tv[qq - 1]; ti[qq] = ti[qq - 1]; }
              else { tv[qq] = v; ti[qq] = s; placed = true; }
            }
          }
          if (!placed) { tv[0] = v; ti[0] = s; }
        }
      }
    }
    MERGE_XOR(16)                               // quads {0,1} / {2,3}
    MERGE_XOR(32)                               // all 4 quads -> top-8 of 32 s
    if (quad == 0) {
      #pragma unroll
      for (int k = 0; k < 8; ++k) {
        candv[wv][qf * 16 + n16][k] = tv[k];
        candi[wv][qf * 16 + n16][k] = ti[k];
      }
    }
  }
  __syncthreads();

  // cross-wave merge: 8 sorted lists per q -> exact top-8 of 256 slots
  if (t < 256) {
    int q = t >> 3, j = t & 7;
    float tv[8]; int ti[8];
    #pragma unroll
    for (int k = 0; k < 8; ++k) { tv[k] = candv[j][q][k]; ti[k] = candi[j][q][k]; }
    MERGE_XOR(1)
    MERGE_XOR(2)
    MERGE_XOR(4)
    if (j == 0) {
      float* cv = ws + WS_CANDV;
      int* ci = (int*)(ws + WS_CANDI);
      long ob = (long)(qbase + q) * CPR2 + (long)stile * 8;
      #pragma unroll
      for (int k = 0; k < 8; ++k) { cv[ob + k] = tv[k]; ci[ob + k] = ti[k]; }
    }
  }
}

// ---------------- K4 v5: register top-16 + shfl merges + shared-kp_w f64 rescore ----------------
// Per block (row b): each thread builds a register-resident sorted top-16 of
// its ~12 candidates (u64 keys: (ord(v)<<32)|(~id) — globally unique); 6
// shfl-xor bitonic merge levels -> per-wave top-16; rank-count over the 4x16
// survivors -> exact block top-16 (2 barriers, zero bank conflicts; replaces
// the 32KB keys[] LDS + 128-barrier tree of v4). Rescore: stage the 16 key
// rows as f64 in LDS; thread i owns kp_w row i -> kp_w read ONCE per block
// (was 16x); 16 f64 accumulators; shfl+LDS reduction. Identical math/outputs.

#define CEK(i, j) { \
  bool g_ = ml[j] > ml[i]; \
  unsigned long long a_ = g_ ? ml[j] : ml[i]; \
  unsigned long long b_ = g_ ? ml[i] : ml[j]; \
  ml[i] = a_; ml[j] = b_; }

#define MERGE16(D) { \
  unsigned long long pv[16]; \
  _Pragma("unroll") \
  for (int k_ = 0; k_ < 16; ++k_) pv[k_] = __shfl_xor(ml[k_], D); \
  _Pragma("unroll") \
  for (int k_ = 0; k_ < 16; ++k_) { \
    unsigned long long o_ = pv[15 - k_]; if (o_ > ml[k_]) ml[k_] = o_; } \
  CEK(0,8) CEK(1,9) CEK(2,10) CEK(3,11) CEK(4,12) CEK(5,13) CEK(6,14) CEK(7,15) \
  CEK(0,4) CEK(1,5) CEK(2,6) CEK(3,7) CEK(8,12) CEK(9,13) CEK(10,14) CEK(11,15) \
  CEK(0,2) CEK(1,3) CEK(4,6) CEK(5,7) CEK(8,10) CEK(9,11) CEK(12,14) CEK(13,15) \
  CEK(0,1) CEK(2,3) CEK(4,5) CEK(6,7) CEK(8,9) CEK(10,11) CEK(12,13) CEK(14,15) }

__global__ void __launch_bounds__(256) k_topk(const void* key_store, const void* idx_store,
                                              float* ws, void* dout) {
  __shared__ double krs[16][256];               // 32 KB: 16 cand key rows (f64)
  __shared__ unsigned long long wl[64];         // 4 waves x 16
  __shared__ unsigned long long res[16];
  __shared__ int cidx[16];
  __shared__ double rv[16];
  __shared__ double dred[4][16], nred[4][16];
  const int isbf = *(const int*)ws;
  const int t = threadIdx.x, b = blockIdx.x;
  const int lane = t & 63, wv = t >> 6;

  // ---- phase 1: per-thread register top-16 over ~12 candidates ----
  unsigned long long ml[16];
  #pragma unroll
  for (int q = 0; q < 16; ++q) ml[q] = 0ull;
  {
    const float* cv = ws + WS_CANDV;
    const int* ci = (const int*)(ws + WS_CANDI);
    long base = (long)b * CPR2;
    for (int cc = t; cc < CPR2; cc += 256) {
      float v = cv[base + cc];
      unsigned id = (unsigned)ci[base + cc];
      unsigned bb = __float_as_uint(v);
      unsigned o = (bb & 0x80000000u) ? ~bb : (bb | 0x80000000u);
      unsigned long long key = ((unsigned long long)o << 32) |
                               (unsigned long long)(0xFFFFFFFFu - id);
      if (key > ml[15]) {
        bool placed = false;
        #pragma unroll
        for (int q = 15; q >= 1; --q) {
          if (!placed) {
            if (key > ml[q - 1]) ml[q] = ml[q - 1];
            else { ml[q] = key; placed = true; }
          }
        }
        if (!placed) ml[0] = key;
      }
    }
  }
  // ---- phase 2: wave-level bitonic merges -> per-wave top-16 ----
  MERGE16(1) MERGE16(2) MERGE16(4) MERGE16(8) MERGE16(16) MERGE16(32)
  if (lane == 0) {
    #pragma unroll
    for (int k = 0; k < 16; ++k) wl[wv * 16 + k] = ml[k];
  }
  __syncthreads();
  // ---- phase 3: rank-count over the 64 survivors (keys unique) ----
  if (t < 64) {
    unsigned long long my = wl[t];
    int rank = 0;
    for (int m = 0; m < 64; ++m) {
      unsigned long long o = __shfl(my, m);
      rank += (o > my) ? 1 : 0;
    }
    if (rank < 16) res[rank] = my;
  }
  __syncthreads();
  if (t < 16) cidx[t] = (int)(0xFFFFFFFFu - (unsigned)(res[t] & 0xFFFFFFFFu));
  __syncthreads();
  // ---- phase 4: stage 16 candidate key rows as f64 in LDS ----
  for (int idx = t; idx < 16 * 256; idx += 256) {
    int c = idx >> 8, j = idx & 255;
    long m = (long)cidx[c];
    krs[c][j] = (double)ldf(key_store, m * 256 + j, isbf);
  }
  __syncthreads();
  // ---- phase 5: f64 rescore, thread t owns kp_w row t ----
  {
    double s[16];
    double kb = (double)ws[WS_KPB + t];
    #pragma unroll
    for (int c = 0; c < 16; ++c) s[c] = kb;
    const float* wrow = ws + WS_KPW + (long)t * 256;
    for (int j = 0; j < 256; ++j) {
      double w = (double)wrow[j];
      #pragma unroll
      for (int c = 0; c < 16; ++c) s[c] += w * krs[c][j];
    }
    double pk_i = (double)ws[WS_PKN + (long)b * 256 + t];
    #pragma unroll
    for (int c = 0; c < 16; ++c) {
      double d = s[c] * pk_i;
      double n = s[c] * s[c];
      d += __shfl_xor(d, 1);  n += __shfl_xor(n, 1);
      d += __shfl_xor(d, 2);  n += __shfl_xor(n, 2);
      d += __shfl_xor(d, 4);  n += __shfl_xor(n, 4);
      d += __shfl_xor(d, 8);  n += __shfl_xor(n, 8);
      d += __shfl_xor(d, 16); n += __shfl_xor(n, 16);
      d += __shfl_xor(d, 32); n += __shfl_xor(n, 32);
      if (lane == 0) { dred[wv][c] = d; nred[wv][c] = n; }
    }
  }
  __syncthreads();
  if (t < 16) {
    double dp = dred[0][t] + dred[1][t] + dred[2][t] + dred[3][t];
    double nr = nred[0][t] + nred[1][t] + nred[2][t] + nred[3][t];
    rv[t] = dp / fmax(sqrt(nr), 1e-8);
  }
  __syncthreads();
  // ---- phase 6: final top-8 by rescored value (unchanged) ----
  if (t == 0) {
    int ordr[16];
    for (int q = 0; q < 16; ++q) ordr[q] = q;
    for (int a = 0; a < 8; ++a) {
      int best = a;
      for (int x = a + 1; x < 16; ++x) {
        int xi = ordr[x], bi = ordr[best];
        if (rv[xi] > rv[bi] || (rv[xi] == rv[bi] && cidx[xi] < cidx[bi])) best = x;
      }
      int tmp = ordr[a]; ordr[a] = ordr[best]; ordr[best] = tmp;
    }
    int* seli = (int*)(ws + WS_SELI);
    for (int r = 0; r < 8; ++r) {
      int m = cidx[ordr[r]];
      stf(dout, OUT_IDX + b * 8 + r, (float)m, isbf);
      stf(dout, OUT_SIMV + b * 8 + r, (float)rv[ordr[r]], isbf);
      stf(dout, OUT_SELIDX + b * 8 + r, ldf(idx_store, m, isbf), isbf);
      seli[b * 8 + r] = m;
    }
  }
}

// ---------------- K5: GAT compose + count-sketch + circular conv ----------------
__global__ void k_compose(const void* value_store, const int* h1, const int* h2,
                          float* ws, void* dout) {
  __shared__ float feats[9][512];
  __shared__ float Wh[9][512];
  __shared__ float g0[9][8];
  __shared__ float sd_[2][9][8];
  __shared__ float psi1[512], psi2[512], pooled[512];
  __shared__ float wk[9];
  __shared__ float redz[40];
  __shared__ int sel[8];
  const int isbf = *(const int*)ws;
  const int t = threadIdx.x, b = blockIdx.x;
  if (t < 8) sel[t] = ((const int*)(ws + WS_SELI))[b * 8 + t];
  feats[0][t]       = ws[WS_OUT + (long)b * 512 + t];
  feats[0][t + 256] = ws[WS_OUT + (long)b * 512 + t + 256];
  __syncthreads();
  for (int n = 0; n < 16; ++n) {
    int e = t + 256 * n;
    int r = e >> 9, d = e & 511;
    feats[1 + r][d] = ldf(value_store, (long)sel[r] * 512 + d, isbf);
  }
  __syncthreads();
  {
    const int he0 = t, he1 = t + 256;
    float a0[9] = {}, a1[9] = {};
    const float* gw = ws + WS_GATW;
    for (int d = 0; d < 512; ++d) {
      float w0 = gw[(long)d * 512 + he0];
      float w1 = gw[(long)d * 512 + he1];
      #pragma unroll
      for (int k = 0; k < 9; ++k) {
        float a = feats[k][d];
        a0[k] += a * w0;
        a1[k] += a * w1;
      }
    }
    #pragma unroll
    for (int k = 0; k < 9; ++k) { Wh[k][he0] = a0[k]; Wh[k][he1] = a1[k]; }
  }
  __syncthreads();
  if (t < 144) {
    int k = t >> 4, rem = t & 15, hh = rem >> 1, sdx = rem & 1;
    const float* av = ws + (sdx ? WS_GAD : WS_GAS) + hh * 64;
    float s = 0.f;
    for (int e = 0; e < 64; ++e) s += Wh[k][hh * 64 + e] * av[e];
    sd_[sdx][k][hh] = s;
  }
  __syncthreads();
  if (t < 8) {
    float L[9], mx = -3e38f;
    for (int j = 0; j < 9; ++j) {
      float x = sd_[0][0][t] + sd_[1][j][t];
      L[j] = x > 0.f ? x : 0.2f * x;
      mx = fmaxf(mx, L[j]);
    }
    float ssum = 0.f;
    for (int j = 0; j < 9; ++j) { L[j] = expf(L[j] - mx); ssum += L[j]; }
    for (int j = 0; j < 9; ++j) g0[j][t] = L[j] / ssum;
  }
  __syncthreads();
  for (int n = 0; n < 3; ++n) {
    int e = t + 256 * n;
    if (e < 648) {
      int i = e / 72, rem = e % 72, j = rem >> 3, hh = rem & 7;
      float v = (i == 0) ? g0[j][hh] : ((i == j) ? 1.0f : 0.0f);
      stf(dout, OUT_GATT + (long)b * 648 + e, v, isbf);
    }
  }
  __syncthreads();
  #pragma unroll
  for (int i = 0; i < 9; ++i) {
    for (int half = 0; half < 2; ++half) {
      int d = t + half * 256;
      float x;
      if (i == 0) {
        int hh = d >> 6;
        x = 0.f;
        #pragma unroll
        for (int j = 0; j < 9; ++j) x += g0[j][hh] * Wh[j][d];
      } else x = Wh[i][d];
      feats[i][d] = x > 0.f ? x : expm1f(x);
    }
  }
  __syncthreads();
  {
    float part[9];
    const float* aw = ws + WS_GAW;
    #pragma unroll
    for (int k = 0; k < 9; ++k)
      part[k] = feats[k][t] * aw[t] + feats[k][t + 256] * aw[t + 256];
    #pragma unroll
    for (int k = 0; k < 9; ++k) {
      float s = part[k];
      s += __shfl_xor(s, 1);  s += __shfl_xor(s, 2);  s += __shfl_xor(s, 4);
      s += __shfl_xor(s, 8);  s += __shfl_xor(s, 16); s += __shfl_xor(s, 32);
      if ((t & 63) == 0) redz[(t >> 6) * 9 + k] = s;
    }
  }
  __syncthreads();
  if (t == 0) {
    float l[9], mx = -3e38f;
    for (int k = 0; k < 9; ++k) {
      l[k] = redz[k] + redz[9 + k] + redz[18 + k] + redz[27 + k] + ws[WS_GAB];
      mx = fmaxf(mx, l[k]);
    }
    float ssum = 0.f;
    for (int k = 0; k < 9; ++k) { l[k] = expf(l[k] - mx); ssum += l[k]; }
    for (int k = 0; k < 9; ++k) wk[k] = l[k] / ssum;
  }
  __syncthreads();
  for (int half = 0; half < 2; ++half) {
    int d = t + half * 256;
    float s = 0.f;
    #pragma unroll
    for (int k = 0; k < 9; ++k) s += wk[k] * feats[k][d];
    pooled[d] = s;
    psi1[d] = 0.f; psi2[d] = 0.f;
  }
  __syncthreads();
  for (int half = 0; half < 2; ++half) {
    int j = t + half * 256;
    atomicAdd(&psi1[h1[j]], ws[WS_OUT + (long)b * 512 + j] * ws[WS_S1 + j]);
    atomicAdd(&psi2[h2[j]], pooled[j] * ws[WS_S2 + j]);
  }
  __syncthreads();
  for (int half = 0; half < 2; ++half) {
    int tt = t + half * 256;
    float s = 0.f;
    for (int j = 0; j < 512; ++j) s += psi1[j] * psi2[(tt - j) & 511];
    stf(dout, OUT_COMPOSED + (long)b * 1024 + tt, s, isbf);
    stf(dout, OUT_COMPOSED + (long)b * 1024 + 512 + tt,
        ws[WS_OUT + (long)b * 512 + tt], isbf);
  }
}

// ---------------- launch ----------------
extern "C" void kernel_launch(void* const* d_in, const int* in_sizes, int n_in,
                              void* d_out, int out_size, void* d_ws, size_t ws_size,
                              hipStream_t stream) {
  float* ws = (float*)d_ws;
  k_detect<<<1, 64, 0, stream>>>((const unsigned*)d_in[15], (int*)d_ws);
  k_prep<<<512, 256, 0, stream>>>(d_in[1], d_in[6], d_in[7], d_in[0], d_in[8],
                                  d_in[9], d_in[10], d_in[11], d_in[12],
                                  d_in[15], d_in[16], ws);
  k_pk<<<64, 256, 0, stream>>>(ws);
  k_ps<<<NPS, 256, 0, stream>>>(d_in[3], ws);
  // v4: 16 qtiles x 391 stiles, XCD-affine; 49 groups x 128 = 6272 blocks
  k_sim<<<49 * 128, 512, 0, stream>>>(ws);
  k_topk<<<512, 256, 0, stream>>>(d_in[3], d_in[5], ws, d_out);
  k_compose<<<512, 256, 0, stream>>>(d_in[4], (const int*)d_in[13],
                                     (const int*)d_in[14], ws, d_out);
}